// Round 7
// baseline (341.646 us; speedup 1.0000x reference)
//
#include <hip/hip_runtime.h>
#include <hip/hip_bf16.h>

#define O_N 128
#define D_N 128
#define F_LS 64
#define T_MAX 128
#define FE_N 16
#define H_GRU 64
#define NH 128
#define NO 64
#define PH 128

typedef _Float16 f16;
typedef __fp16 hf2 __attribute__((ext_vector_type(2)));
typedef f16 f16x4 __attribute__((ext_vector_type(4)));
typedef f16 f16x8 __attribute__((ext_vector_type(8)));
typedef float f32x4 __attribute__((ext_vector_type(4)));

__device__ __forceinline__ float fast_sigmoid(float x) {
    return __builtin_amdgcn_rcpf(1.f + __expf(-x));
}

// ---- fused: encoders (blocks 0..255) + counting sort (block 256) ----------
// enc: PA / transposed-PB (bp1 folded); also zeroes d_out.
// sort: lengths -> perm, descending, 256 threads.
__global__ __launch_bounds__(256) void k_pre(
    const float* __restrict__ O_feats, const float* __restrict__ D_feats,
    const float* __restrict__ WO1, const float* __restrict__ bO1,
    const float* __restrict__ WO2, const float* __restrict__ bO2,
    const float* __restrict__ WO3, const float* __restrict__ bO3,
    const float* __restrict__ WD1, const float* __restrict__ bD1,
    const float* __restrict__ WD2, const float* __restrict__ bD2,
    const float* __restrict__ WD3, const float* __restrict__ bD3,
    const float* __restrict__ Wp1, const float* __restrict__ bp1,
    const int* __restrict__ lengths,
    float* __restrict__ PA, float* __restrict__ PBt,
    int* __restrict__ perm, float* __restrict__ d_out)
{
    const int t = threadIdx.x;
    if (blockIdx.x == 256) {
        // ---------------- counting sort, 256 threads ----------------
        __shared__ int cnt[130];
        __shared__ int suf[130];
        if (t < 130) cnt[t] = 0;
        __syncthreads();
        for (int i = t; i < 16384; i += 256) atomicAdd(&cnt[lengths[i]], 1);
        __syncthreads();
        if (t < 130) suf[t] = cnt[t];
        __syncthreads();
        for (int d = 1; d < 130; d <<= 1) {
            int v = 0;
            if (t < 130) { v = suf[t]; if (t + d < 130) v += suf[t + d]; }
            __syncthreads();
            if (t < 130) suf[t] = v;
            __syncthreads();
        }
        if (t < 129) cnt[t] = (t + 1 < 130) ? suf[t + 1] : 0;
        __syncthreads();
        for (int i = t; i < 16384; i += 256) {
            int pos = atomicAdd(&cnt[lengths[i]], 1);
            perm[pos] = i;
        }
        return;
    }

    // ---------------- encoder, threads 0..127 active ----------------
    __shared__ float h1[NH];
    __shared__ float h2[NH];
    __shared__ float ev[NO];
    const int b = blockIdx.x;
    const int enc = b >> 7;
    const int row = b & 127;
    if (b == 0 && t == 0) d_out[0] = 0.f;

    const float* x  = (enc ? D_feats : O_feats) + row * F_LS;
    const float* W1 = enc ? WD1 : WO1;  const float* b1 = enc ? bD1 : bO1;
    const float* W2 = enc ? WD2 : WO2;  const float* b2 = enc ? bD2 : bO2;
    const float* W3 = enc ? WD3 : WO3;  const float* b3 = enc ? bD3 : bO3;

    if (t < 128) {
        float a = b1[t];
        #pragma unroll 8
        for (int k = 0; k < F_LS; ++k) a += x[k] * W1[k * NH + t];
        h1[t] = fmaxf(a, 0.f);
    }
    __syncthreads();

    if (t < 128) {
        float a = b2[t];
        #pragma unroll 8
        for (int k = 0; k < NH; ++k) a += h1[k] * W2[k * NH + t];
        h2[t] = fmaxf(a, 0.f);
    }
    __syncthreads();

    if (t < NO) {
        float a = b3[t];
        #pragma unroll 8
        for (int k = 0; k < NH; ++k) a += h2[k] * W3[k * NO + t];
        ev[t] = a;
    }
    __syncthreads();

    if (t < 128) {
        const float* Wp = Wp1 + (enc ? NO * PH : 0);
        float a = 0.f;
        #pragma unroll 8
        for (int k = 0; k < NO; ++k) a += ev[k] * Wp[k * PH + t];
        if (enc) PBt[t * 128 + row] = a + bp1[t];   // transposed + bias folded
        else     PA[row * PH + t] = a;
    }
}

// ---- GRU: independent 4-wave blocks, BALANCED co-residency mapping --------
// grid 1024 x 256 (4 blocks/CU). Dispatch co-locates blocks {b,b+256,b+512,
// b+768}; map them to groups {2b, 2b+1, 1022-2b, 1023-2b}: per-CU total
// ~256 steps (vs 192..320 identity), top-two lengths EQUAL (they finish
// together -> no 1-wave tail), bottom-two equal and short. Fitted model
// T_step(c)=670c+150 -> uniform ~77us wall. x staged through LDS double
// buffer in 8-step phases via global_load_lds (vmcnt(0) drain amortized to
// once per 8 steps); xbuf transposed [row][chunk][pair] (4-way conflict).
// Wave w owns hidden cols [16w,16w+16); lane(q,n): pair n, cols 16w+4q+0..3.
// x-first MFMA ordering. Pair-score MLP fused in epilogue.
__global__ __launch_bounds__(256, 4) void k_gru(
    const float* __restrict__ seqs, const int* __restrict__ lengths,
    const int* __restrict__ perm,
    const float* __restrict__ W_ih, const float* __restrict__ b_ih,
    const float* __restrict__ W_hh, const float* __restrict__ b_hh,
    const float* __restrict__ Ws, const float* __restrict__ bs,
    const float* __restrict__ PA, const float* __restrict__ PBt,
    const float* __restrict__ Wp2, const float* __restrict__ bp2,
    float* __restrict__ d_out)
{
    __shared__ __align__(16) f16 hbuf[2][16 * 72];      // [buf][pair][64+8 pad]
    __shared__ __align__(16) float4 xbuf[2][8][64];     // [buf][row][chunk*16+pair]
    __shared__ float red[64];
    const int tid = threadIdx.x;
    const int w  = tid >> 6;
    const int l  = tid & 63;
    const int q  = l >> 4;
    const int n  = l & 15;
    const int c  = w * 16 + n;          // W-frag column (m-row of A-tile)
    const int colbase = w * 16 + q * 4; // this lane's 4 hidden cols
    // balanced co-residency mapping (bijective):
    const int b2 = blockIdx.x & 255;
    const int j  = blockIdx.x >> 8;
    const int g  = (j == 0) ? 2 * b2
                 : (j == 1) ? 2 * b2 + 1
                 : (j == 2) ? 1022 - 2 * b2
                            : 1023 - 2 * b2;
    const int pb = g * 16;
    const float S_RZ = -1.4426950408889634f;   // -log2(e)
    const float S_N  =  2.8853900817779268f;   // 2*log2(e)

    // W fragments (A-operand via m=lane&15):
    f16x8 wh[3][2], wi[3];
    #pragma unroll
    for (int gg = 0; gg < 3; ++gg) {
        const int gb = gg * 64;
        const float s = (gg < 2) ? S_RZ : S_N;
        #pragma unroll
        for (int ks = 0; ks < 2; ++ks)
            #pragma unroll
            for (int jj = 0; jj < 8; ++jj)
                wh[gg][ks][jj] = (f16)(W_hh[(ks * 32 + q * 8 + jj) * 192 + gb + c] * s);
        #pragma unroll
        for (int jj = 0; jj < 8; ++jj) {
            int k = q * 8 + jj;
            wi[gg][jj] = (k < FE_N) ? (f16)(W_ih[k * 192 + gb + c] * s) : (f16)0.f;
        }
    }
    // per-reg bias C-vectors and Ws for this lane's 4 cols
    f32x4 c_r, c_z, c_hn, c_xn;
    float wsc[4];
    #pragma unroll
    for (int r = 0; r < 4; ++r) {
        int col = colbase + r;
        c_r[r]  = S_RZ * (b_ih[col] + b_hh[col]);
        c_z[r]  = S_RZ * (b_ih[64 + col] + b_hh[64 + col]);
        c_hn[r] = S_N * b_hh[128 + col];
        c_xn[r] = S_N * b_ih[128 + col];
        wsc[r]  = Ws[col];
    }
    const int myp   = perm[pb + n];      // this lane's pair
    const int mylen = lengths[myp];
    int ml = mylen;
    ml = max(ml, __shfl_xor(ml, 1));
    ml = max(ml, __shfl_xor(ml, 2));
    ml = max(ml, __shfl_xor(ml, 4));
    ml = max(ml, __shfl_xor(ml, 8));
    const int maxlen = __builtin_amdgcn_readfirstlane(ml);

    // staging source: lane l covers slot l = (chunk l>>4, pair l&15)
    const float* xsrc = seqs + (size_t)perm[pb + (l & 15)] * (T_MAX * FE_N)
                       + (l >> 4) * 4;

    // zero h buffer 0 (2304 B = 144 x 16 B)
    if (tid < 144) { f16x8 z8 = {}; *(f16x8*)&hbuf[0][tid * 8] = z8; }

    // stage phase 0 (rows 0..7): wave w loads rows {w, w+4}
    #pragma unroll
    for (int rr = 0; rr < 2; ++rr) {
        const int r8 = w + rr * 4;
        __builtin_amdgcn_global_load_lds(
            (const __attribute__((address_space(1))) void*)(xsrc + (size_t)r8 * FE_N),
            (__attribute__((address_space(3))) void*)&xbuf[0][r8][0], 16, 0, 0);
    }
    float hold[4] = {0.f, 0.f, 0.f, 0.f};
    const f16x8 zero8 = {};
    __syncthreads();   // drains phase-0 staging + hbuf zero

    #pragma unroll 1
    for (int t = 0; t < maxlen; ++t) {
        const int cur = t & 1;
        const int xb  = (t >> 3) & 1;
        const int row = t & 7;
        const f16* hb  = hbuf[cur];
        f16*       hbw = hbuf[cur ^ 1];
        // issue LDS reads first (latency), staging + x-convert fill the gap
        f16x8 bh0 = *(const f16x8*)&hb[n * 72 + 8 * q];
        f16x8 bh1 = *(const f16x8*)&hb[n * 72 + 32 + 8 * q];

        // stage NEXT phase once per 8 steps (block-uniform condition)
        if (row == 0 && t + 8 < maxlen) {
            const int nb = xb ^ 1;
            #pragma unroll
            for (int rr = 0; rr < 2; ++rr) {
                const int rl = w + rr * 4;
                int rg = t + 8 + rl;
                rg = rg < T_MAX ? rg : T_MAX - 1;   // rows always allocated
                __builtin_amdgcn_global_load_lds(
                    (const __attribute__((address_space(1))) void*)(xsrc + (size_t)rg * FE_N),
                    (__attribute__((address_space(3))) void*)&xbuf[nb][rl][0], 16, 0, 0);
            }
        }

        f16x8 ax = zero8;                 // q>=2 lanes contribute zeros (K pad)
        if (q < 2) {
            float4 a0 = xbuf[xb][row][32 * q + n];        // chunk 2q
            float4 a1 = xbuf[xb][row][32 * q + 16 + n];   // chunk 2q+1
            union { f16x8 v8; hf2 v2[4]; } u;
            u.v2[0] = __builtin_amdgcn_cvt_pkrtz(a0.x, a0.y);
            u.v2[1] = __builtin_amdgcn_cvt_pkrtz(a0.z, a0.w);
            u.v2[2] = __builtin_amdgcn_cvt_pkrtz(a1.x, a1.y);
            u.v2[3] = __builtin_amdgcn_cvt_pkrtz(a1.z, a1.w);
            ax = u.v8;
        }

        // x-first MFMA chains (no LDS dep on first op of r/z/xn)
        f32x4 ar = __builtin_amdgcn_mfma_f32_16x16x32_f16(wi[0], ax, c_r, 0, 0, 0);
        f32x4 az = __builtin_amdgcn_mfma_f32_16x16x32_f16(wi[1], ax, c_z, 0, 0, 0);
        f32x4 xn = __builtin_amdgcn_mfma_f32_16x16x32_f16(wi[2], ax, c_xn, 0, 0, 0);
        ar = __builtin_amdgcn_mfma_f32_16x16x32_f16(wh[0][0], bh0, ar, 0, 0, 0);
        ar = __builtin_amdgcn_mfma_f32_16x16x32_f16(wh[0][1], bh1, ar, 0, 0, 0);
        az = __builtin_amdgcn_mfma_f32_16x16x32_f16(wh[1][0], bh0, az, 0, 0, 0);
        az = __builtin_amdgcn_mfma_f32_16x16x32_f16(wh[1][1], bh1, az, 0, 0, 0);
        f32x4 hn = __builtin_amdgcn_mfma_f32_16x16x32_f16(wh[2][0], bh0, c_hn, 0, 0, 0);
        hn = __builtin_amdgcn_mfma_f32_16x16x32_f16(wh[2][1], bh1, hn, 0, 0, 0);

        const bool live = (t < mylen);
        #pragma unroll
        for (int r = 0; r < 4; ++r) {
            float rg    = __builtin_amdgcn_rcpf(1.f + __builtin_amdgcn_exp2f(ar[r]));
            float zg    = __builtin_amdgcn_rcpf(1.f + __builtin_amdgcn_exp2f(az[r]));
            float inner = fmaf(rg, hn[r], xn[r]);
            float nn    = fmaf(-2.f, __builtin_amdgcn_rcpf(1.f + __builtin_amdgcn_exp2f(inner)), 1.f);
            float hnew  = fmaf(zg, hold[r] - nn, nn);
            hold[r] = live ? hnew : hold[r];
        }
        union { f16x4 v4; hf2 v2[2]; } hu;
        hu.v2[0] = __builtin_amdgcn_cvt_pkrtz(hold[0], hold[1]);
        hu.v2[1] = __builtin_amdgcn_cvt_pkrtz(hold[2], hold[3]);
        *(f16x4*)&hbw[n * 72 + colbase] = hu.v4;
        __syncthreads();
    }

    // ---- epilogue: p_seq = sigmoid(h @ Ws + bs); fused pair-score MLP ----
    float part = hold[0] * wsc[0] + hold[1] * wsc[1] +
                 hold[2] * wsc[2] + hold[3] * wsc[3];
    part += __shfl_xor(part, 16);
    part += __shfl_xor(part, 32);          // sum over q: wave-w partial for pair n
    if (l < 16) red[w * 16 + n] = part;
    __syncthreads();

    // 16 threads per pair: s_pair = softplus(Wp2 . relu(PA_i + PBt_j))
    const int pp = tid >> 4;               // pair 0..15
    const int u  = tid & 15;
    const int pidx = perm[pb + pp];
    const int ii = pidx >> 7;
    const int jj = pidx & 127;
    float acc = 0.f;
    #pragma unroll
    for (int cc = u; cc < PH; cc += 16)
        acc += Wp2[cc] * fmaxf(PA[ii * PH + cc] + PBt[cc * 128 + jj], 0.f);
    acc += __shfl_xor(acc, 1);
    acc += __shfl_xor(acc, 2);
    acc += __shfl_xor(acc, 4);
    acc += __shfl_xor(acc, 8);
    float contrib = 0.f;
    if (u == 0) {
        float z  = acc + bp2[0];
        float sp = fmaxf(z, 0.f) + log1pf(__expf(-fabsf(z)));
        float s  = red[pp] + red[16 + pp] + red[32 + pp] + red[48 + pp];
        float pv = fast_sigmoid(s + bs[0]);
        contrib  = sp * pv;
    }
    __syncthreads();
    if (u == 0) red[pp] = contrib;
    __syncthreads();
    if (tid == 0) {
        float tot = 0.f;
        #pragma unroll
        for (int k = 0; k < 16; ++k) tot += red[k];
        atomicAdd(d_out, tot);
    }
}

extern "C" void kernel_launch(void* const* d_in, const int* in_sizes, int n_in,
                              void* d_out, int out_size, void* d_ws, size_t ws_size,
                              hipStream_t stream)
{
    const float* O_feats = (const float*)d_in[0];
    const float* D_feats = (const float*)d_in[1];
    const float* seqs    = (const float*)d_in[2];
    const int*   lengths = (const int*)d_in[3];
    const float* WO1 = (const float*)d_in[4];  const float* bO1 = (const float*)d_in[5];
    const float* WO2 = (const float*)d_in[6];  const float* bO2 = (const float*)d_in[7];
    const float* WO3 = (const float*)d_in[8];  const float* bO3 = (const float*)d_in[9];
    const float* WD1 = (const float*)d_in[10]; const float* bD1 = (const float*)d_in[11];
    const float* WD2 = (const float*)d_in[12]; const float* bD2 = (const float*)d_in[13];
    const float* WD3 = (const float*)d_in[14]; const float* bD3 = (const float*)d_in[15];
    const float* Wp1 = (const float*)d_in[16]; const float* bp1 = (const float*)d_in[17];
    const float* Wp2 = (const float*)d_in[18]; const float* bp2 = (const float*)d_in[19];
    const float* W_ih = (const float*)d_in[20]; const float* b_ih = (const float*)d_in[21];
    const float* W_hh = (const float*)d_in[22]; const float* b_hh = (const float*)d_in[23];
    const float* Ws   = (const float*)d_in[24]; const float* bs   = (const float*)d_in[25];

    float* out    = (float*)d_out;
    float* PA     = (float*)d_ws;              // 16384 f
    float* PBt    = PA + 128 * 128;            // 16384 f (transposed, bp1 folded)
    int*   perm   = (int*)(PBt + 128 * 128);   // 16384 i

    k_pre<<<257, 256, 0, stream>>>(O_feats, D_feats,
                                   WO1, bO1, WO2, bO2, WO3, bO3,
                                   WD1, bD1, WD2, bD2, WD3, bD3,
                                   Wp1, bp1, lengths, PA, PBt, perm, out);
    k_gru<<<1024, 256, 0, stream>>>(seqs, lengths, perm, W_ih, b_ih, W_hh, b_hh,
                                    Ws, bs, PA, PBt, Wp2, bp2, out);
}